// Round 4
// baseline (956.539 us; speedup 1.0000x reference)
//
#include <hip/hip_runtime.h>
#include <math.h>

#define NENT   100000
#define NREL   50
#define DIM    64
#define NEDGE  1000000
#define SCAN_BLOCKS ((NENT + 255) / 256)   // 391

// wr[r][d] = sum_k W[d][k] * rel[r][k]  (head half); wrt uses W[64+d][k]
__global__ void wr_kernel(const float* __restrict__ W, const float* __restrict__ rel,
                          float* __restrict__ wrh, float* __restrict__ wrt) {
    int id = blockIdx.x * blockDim.x + threadIdx.x;
    if (id >= NREL * DIM) return;
    int r = id / DIM, d = id % DIM;
    const float* wh = W + (size_t)d * DIM;
    const float* wt = W + (size_t)(DIM + d) * DIM;
    const float* rr = rel + (size_t)r * DIM;
    float ah = 0.f, at = 0.f;
    for (int k = 0; k < DIM; ++k) {
        ah += wh[k] * rr[k];
        at += wt[k] * rr[k];
    }
    wrh[id] = ah;
    wrt[id] = at;
}

__global__ void hist_kernel(const int* __restrict__ head, int* __restrict__ cnt) {
    int i = blockIdx.x * blockDim.x + threadIdx.x;
    if (i < NEDGE) atomicAdd(&cnt[head[i]], 1);
}

__global__ void scan_block_kernel(const int* __restrict__ cnt, int* __restrict__ off,
                                  int* __restrict__ bsum) {
    __shared__ int s[256];
    int i = blockIdx.x * 256 + threadIdx.x;
    int v = (i < NENT) ? cnt[i] : 0;
    s[threadIdx.x] = v;
    __syncthreads();
    for (int dlt = 1; dlt < 256; dlt <<= 1) {
        int t = (threadIdx.x >= dlt) ? s[threadIdx.x - dlt] : 0;
        __syncthreads();
        s[threadIdx.x] += t;
        __syncthreads();
    }
    if (i < NENT) off[i] = s[threadIdx.x] - v;   // exclusive within block
    if (threadIdx.x == 255) bsum[blockIdx.x] = s[255];
}

__global__ void scan_bsum_kernel(int* __restrict__ bsum, int nb) {
    if (blockIdx.x == 0 && threadIdx.x == 0) {
        int acc = 0;
        for (int i = 0; i < nb; ++i) { int v = bsum[i]; bsum[i] = acc; acc += v; }
    }
}

__global__ void add_bsum_kernel(int* __restrict__ off, const int* __restrict__ bsum) {
    int i = blockIdx.x * 256 + threadIdx.x;
    if (i < NENT) off[i] += bsum[blockIdx.x];
}

__global__ void scatter_kernel(const int* __restrict__ head, const int* __restrict__ tail,
                               const int* __restrict__ etype, const int* __restrict__ off,
                               int* __restrict__ fill, int* __restrict__ s_tail,
                               int* __restrict__ s_et) {
    int i = blockIdx.x * blockDim.x + threadIdx.x;
    if (i >= NEDGE) return;
    int h = head[i];
    int pos = off[h] + atomicAdd(&fill[h], 1);
    s_tail[pos] = tail[i];
    s_et[pos]   = etype[i];
}

// One 64-lane wave per head entity; lane = feature dim.
__global__ __launch_bounds__(256) void hop_kernel(
    const float* __restrict__ emb, const int* __restrict__ off, const int* __restrict__ cnt,
    const int* __restrict__ s_tail, const int* __restrict__ s_et,
    const float* __restrict__ wrh, const float* __restrict__ wrt,
    const float* __restrict__ res_in, float* __restrict__ res_out,
    float* __restrict__ emb_out) {
    __shared__ float lwh[NREL * DIM];
    __shared__ float lwt[NREL * DIM];
    for (int i = threadIdx.x; i < NREL * DIM; i += 256) {
        lwh[i] = wrh[i];
        lwt[i] = wrt[i];
    }
    __syncthreads();

    int wid  = blockIdx.x * 4 + (threadIdx.x >> 6);
    int lane = threadIdx.x & 63;
    if (wid >= NENT) return;
    int h = wid;

    float embH = emb[(size_t)h * DIM + lane];
    int o = off[h], c = cnt[h];

    // pass 1: segment max of leaky-relu scores
    float m = -1e30f;
    for (int j = 0; j < c; ++j) {
        int tl = s_tail[o + j], et = s_et[o + j];
        float embT = emb[(size_t)tl * DIM + lane];
        float p = embH * lwh[et * DIM + lane] + embT * lwt[et * DIM + lane];
        #pragma unroll
        for (int s = 32; s; s >>= 1) p += __shfl_xor(p, s, 64);
        float e = (p >= 0.f) ? p : 0.2f * p;
        m = fmaxf(m, e);
    }

    // pass 2: denom = sum(w), num[d] = sum(w * emb[tail][d])
    float denom = 0.f, num = 0.f;
    for (int j = 0; j < c; ++j) {
        int tl = s_tail[o + j], et = s_et[o + j];
        float embT = emb[(size_t)tl * DIM + lane];
        float p = embH * lwh[et * DIM + lane] + embT * lwt[et * DIM + lane];
        #pragma unroll
        for (int s = 32; s; s >>= 1) p += __shfl_xor(p, s, 64);
        float e = (p >= 0.f) ? p : 0.2f * p;
        float w = expf(e - m);
        denom += w;
        num   += w * embT;
    }

    float v = embH + ((c > 0) ? (num / denom) : 0.f);

    // L2 normalize across the 64 dims
    float sq = v * v;
    #pragma unroll
    for (int s = 32; s; s >>= 1) sq += __shfl_xor(sq, s, 64);
    float nrm = sqrtf(sq);
    v = v / fmaxf(nrm, 1e-12f);

    if (emb_out) emb_out[(size_t)h * DIM + lane] = v;
    res_out[(size_t)h * DIM + lane] = 0.5f * res_in[(size_t)h * DIM + lane] + v;
}

extern "C" void kernel_launch(void* const* d_in, const int* in_sizes, int n_in,
                              void* d_out, int out_size, void* d_ws, size_t ws_size,
                              hipStream_t stream) {
    const float* ent   = (const float*)d_in[0];
    const float* rel   = (const float*)d_in[1];
    const float* W     = (const float*)d_in[2];
    const int*   head  = (const int*)d_in[3];
    const int*   tail  = (const int*)d_in[4];
    const int*   etype = (const int*)d_in[5];
    float* out = (float*)d_out;

    char* ws = (char*)d_ws;
    size_t pos = 0;
    auto carve = [&](size_t b) -> void* {
        void* p = ws + pos;
        pos += (b + 255) & ~(size_t)255;
        return p;
    };
    float* wrh    = (float*)carve((size_t)NREL * DIM * 4);
    float* wrt    = (float*)carve((size_t)NREL * DIM * 4);
    float* emb_a  = (float*)carve((size_t)NENT * DIM * 4);
    int*   cnt    = (int*)carve((size_t)NENT * 4);
    int*   fill   = (int*)carve((size_t)NENT * 4);
    int*   off    = (int*)carve((size_t)NENT * 4);
    int*   bsum   = (int*)carve((size_t)SCAN_BLOCKS * 4);
    int*   s_tail = (int*)carve((size_t)NEDGE * 4);
    int*   s_et   = (int*)carve((size_t)NEDGE * 4);

    hipMemsetAsync(cnt,  0, (size_t)NENT * 4, stream);
    hipMemsetAsync(fill, 0, (size_t)NENT * 4, stream);

    wr_kernel<<<(NREL * DIM + 255) / 256, 256, 0, stream>>>(W, rel, wrh, wrt);
    hist_kernel<<<(NEDGE + 255) / 256, 256, 0, stream>>>(head, cnt);
    scan_block_kernel<<<SCAN_BLOCKS, 256, 0, stream>>>(cnt, off, bsum);
    scan_bsum_kernel<<<1, 64, 0, stream>>>(bsum, SCAN_BLOCKS);
    add_bsum_kernel<<<SCAN_BLOCKS, 256, 0, stream>>>(off, bsum);
    scatter_kernel<<<(NEDGE + 255) / 256, 256, 0, stream>>>(head, tail, etype, off, fill,
                                                            s_tail, s_et);

    // hop 0: emb_in = input, res_in = input, res_out = out, emb_out = emb_a
    hop_kernel<<<NENT / 4, 256, 0, stream>>>(ent, off, cnt, s_tail, s_et, wrh, wrt,
                                             ent, out, emb_a);
    // hop 1: emb_in = emb_a, res_in = out, res_out = out, emb_out unused
    hop_kernel<<<NENT / 4, 256, 0, stream>>>(emb_a, off, cnt, s_tail, s_et, wrh, wrt,
                                             out, out, nullptr);
}

// Round 6
// 649.492 us; speedup vs baseline: 1.4728x; 1.4728x over previous
//
#include <hip/hip_runtime.h>
#include <math.h>

#define NENT   100000
#define NREL   50
#define DIM    64
#define NEDGE  1000000
#define SCAN_BLOCKS ((NENT + 255) / 256)   // 391

// wr[r][d] = sum_k W[d][k] * rel[r][k]  (head half); wrt uses W[64+d][k]
__global__ void wr_kernel(const float* __restrict__ W, const float* __restrict__ rel,
                          float* __restrict__ wrh, float* __restrict__ wrt) {
    int id = blockIdx.x * blockDim.x + threadIdx.x;
    if (id >= NREL * DIM) return;
    int r = id / DIM, d = id % DIM;
    const float* wh = W + (size_t)d * DIM;
    const float* wt = W + (size_t)(DIM + d) * DIM;
    const float* rr = rel + (size_t)r * DIM;
    float ah = 0.f, at = 0.f;
    for (int k = 0; k < DIM; ++k) {
        ah += wh[k] * rr[k];
        at += wt[k] * rr[k];
    }
    wrh[id] = ah;
    wrt[id] = at;
}

// dH[e][r] = dot(emb[e], wrh[r]); dT[e][r] = dot(emb[e], wrt[r])
// thread-per-entity: 64-float row in VGPRs, uniform weight reads (scalarizable)
__global__ __launch_bounds__(256) void score_kernel(
    const float* __restrict__ emb, const float* __restrict__ wrh,
    const float* __restrict__ wrt, float* __restrict__ dH, float* __restrict__ dT) {
    int e = blockIdx.x * 256 + threadIdx.x;
    if (e >= NENT) return;
    float row[DIM];
    const float4* rp = (const float4*)(emb + (size_t)e * DIM);
    #pragma unroll
    for (int q = 0; q < DIM / 4; ++q) {
        float4 v = rp[q];
        row[4 * q] = v.x; row[4 * q + 1] = v.y; row[4 * q + 2] = v.z; row[4 * q + 3] = v.w;
    }
    for (int r = 0; r < NREL; ++r) {
        const float* wh = wrh + r * DIM;
        const float* wt = wrt + r * DIM;
        float ah = 0.f, at = 0.f;
        #pragma unroll
        for (int k = 0; k < DIM; ++k) {
            ah = fmaf(row[k], wh[k], ah);
            at = fmaf(row[k], wt[k], at);
        }
        dH[(size_t)e * NREL + r] = ah;
        dT[(size_t)e * NREL + r] = at;
    }
}

// histogram + per-edge rank (removes scatter's atomic)
__global__ void hist_kernel(const int* __restrict__ head, int* __restrict__ cnt,
                            int* __restrict__ rank) {
    int i = blockIdx.x * blockDim.x + threadIdx.x;
    if (i < NEDGE) rank[i] = atomicAdd(&cnt[head[i]], 1);
}

__global__ void scan_block_kernel(const int* __restrict__ cnt, int* __restrict__ off,
                                  int* __restrict__ bsum) {
    __shared__ int s[256];
    int i = blockIdx.x * 256 + threadIdx.x;
    int v = (i < NENT) ? cnt[i] : 0;
    s[threadIdx.x] = v;
    __syncthreads();
    for (int dlt = 1; dlt < 256; dlt <<= 1) {
        int t = (threadIdx.x >= dlt) ? s[threadIdx.x - dlt] : 0;
        __syncthreads();
        s[threadIdx.x] += t;
        __syncthreads();
    }
    if (i < NENT) off[i] = s[threadIdx.x] - v;   // exclusive within block
    if (threadIdx.x == 255) bsum[blockIdx.x] = s[255];
}

__global__ void scan_bsum_kernel(int* __restrict__ bsum, int nb) {
    if (blockIdx.x == 0 && threadIdx.x == 0) {
        int acc = 0;
        for (int i = 0; i < nb; ++i) { int v = bsum[i]; bsum[i] = acc; acc += v; }
    }
}

__global__ void add_bsum_kernel(int* __restrict__ off, const int* __restrict__ bsum) {
    int i = blockIdx.x * 256 + threadIdx.x;
    if (i < NENT) off[i] += bsum[blockIdx.x];
}

__global__ void scatter_kernel(const int* __restrict__ head, const int* __restrict__ tail,
                               const int* __restrict__ etype, const int* __restrict__ off,
                               const int* __restrict__ rank, int* __restrict__ s_tail,
                               int* __restrict__ s_et) {
    int i = blockIdx.x * blockDim.x + threadIdx.x;
    if (i >= NEDGE) return;
    int pos = off[head[i]] + rank[i];
    s_tail[pos] = tail[i];
    s_et[pos]   = etype[i];
}

// One 64-lane wave per head entity. No LDS.
// Phase 1 (lane=edge): segment max via one wave-reduce.
// Phase 2 (lane=dim): per edge = 2 uniform score gathers + 1 coalesced row + few VALU.
__global__ __launch_bounds__(256) void hop_kernel(
    const float* __restrict__ emb, const int* __restrict__ off, const int* __restrict__ cnt,
    const int* __restrict__ s_tail, const int* __restrict__ s_et,
    const float* __restrict__ dH, const float* __restrict__ dT,
    const float* __restrict__ res_in, float* __restrict__ res_out,
    float* __restrict__ emb_out) {
    int h    = blockIdx.x * 4 + (threadIdx.x >> 6);
    int lane = threadIdx.x & 63;

    float embH = emb[(size_t)h * DIM + lane];
    int o = off[h], c = cnt[h];
    const float* dHh = dH + (size_t)h * NREL;

    // phase 1: wave max of leaky-relu scores (lane = edge)
    float mloc = -1e30f;
    for (int j0 = 0; j0 < c; j0 += 64) {
        int j = j0 + lane;
        if (j < c) {
            int tl = s_tail[o + j], et = s_et[o + j];
            float s = dHh[et] + dT[(size_t)tl * NREL + et];
            float e = (s >= 0.f) ? s : 0.2f * s;
            mloc = fmaxf(mloc, e);
        }
    }
    #pragma unroll
    for (int s = 32; s; s >>= 1) mloc = fmaxf(mloc, __shfl_xor(mloc, s, 64));
    float m = mloc;

    // phase 2: denom = sum(w), num[lane] = sum(w * emb[tail][lane]) — 2x unrolled
    float denom = 0.f, num = 0.f;
    int j = 0;
    for (; j + 2 <= c; j += 2) {
        int tl0 = s_tail[o + j],     et0 = s_et[o + j];
        int tl1 = s_tail[o + j + 1], et1 = s_et[o + j + 1];
        float t0 = emb[(size_t)tl0 * DIM + lane];
        float t1 = emb[(size_t)tl1 * DIM + lane];
        float s0 = dHh[et0] + dT[(size_t)tl0 * NREL + et0];
        float s1 = dHh[et1] + dT[(size_t)tl1 * NREL + et1];
        float e0 = (s0 >= 0.f) ? s0 : 0.2f * s0;
        float e1 = (s1 >= 0.f) ? s1 : 0.2f * s1;
        float w0 = __expf(e0 - m);
        float w1 = __expf(e1 - m);
        num = fmaf(w0, t0, num);
        num = fmaf(w1, t1, num);
        denom += w0 + w1;
    }
    if (j < c) {
        int tl = s_tail[o + j], et = s_et[o + j];
        float t = emb[(size_t)tl * DIM + lane];
        float s = dHh[et] + dT[(size_t)tl * NREL + et];
        float e = (s >= 0.f) ? s : 0.2f * s;
        float w = __expf(e - m);
        num = fmaf(w, t, num);
        denom += w;
    }

    float v = embH + ((c > 0) ? (num / denom) : 0.f);

    // L2 normalize across the 64 dims
    float sq = v * v;
    #pragma unroll
    for (int s = 32; s; s >>= 1) sq += __shfl_xor(sq, s, 64);
    float nrm = sqrtf(sq);
    v = v / fmaxf(nrm, 1e-12f);

    if (emb_out) emb_out[(size_t)h * DIM + lane] = v;
    res_out[(size_t)h * DIM + lane] = 0.5f * res_in[(size_t)h * DIM + lane] + v;
}

extern "C" void kernel_launch(void* const* d_in, const int* in_sizes, int n_in,
                              void* d_out, int out_size, void* d_ws, size_t ws_size,
                              hipStream_t stream) {
    const float* ent   = (const float*)d_in[0];
    const float* rel   = (const float*)d_in[1];
    const float* W     = (const float*)d_in[2];
    const int*   head  = (const int*)d_in[3];
    const int*   tail  = (const int*)d_in[4];
    const int*   etype = (const int*)d_in[5];
    float* out = (float*)d_out;

    char* ws = (char*)d_ws;
    size_t pos = 0;
    auto carve = [&](size_t b) -> void* {
        void* p = ws + pos;
        pos += (b + 255) & ~(size_t)255;
        return p;
    };
    float* wrh    = (float*)carve((size_t)NREL * DIM * 4);
    float* wrt    = (float*)carve((size_t)NREL * DIM * 4);
    float* emb_a  = (float*)carve((size_t)NENT * DIM * 4);
    int*   cnt    = (int*)carve((size_t)NENT * 4);
    int*   off    = (int*)carve((size_t)NENT * 4);
    int*   bsum   = (int*)carve((size_t)SCAN_BLOCKS * 4);
    int*   s_tail = (int*)carve((size_t)NEDGE * 4);
    int*   s_et   = (int*)carve((size_t)NEDGE * 4);
    int*   rank   = (int*)carve((size_t)NEDGE * 4);
    float* dH     = (float*)carve((size_t)NENT * NREL * 4);
    float* dT     = (float*)carve((size_t)NENT * NREL * 4);

    hipMemsetAsync(cnt, 0, (size_t)NENT * 4, stream);

    wr_kernel<<<(NREL * DIM + 255) / 256, 256, 0, stream>>>(W, rel, wrh, wrt);
    hist_kernel<<<(NEDGE + 255) / 256, 256, 0, stream>>>(head, cnt, rank);
    scan_block_kernel<<<SCAN_BLOCKS, 256, 0, stream>>>(cnt, off, bsum);
    scan_bsum_kernel<<<1, 64, 0, stream>>>(bsum, SCAN_BLOCKS);
    add_bsum_kernel<<<SCAN_BLOCKS, 256, 0, stream>>>(off, bsum);
    scatter_kernel<<<(NEDGE + 255) / 256, 256, 0, stream>>>(head, tail, etype, off, rank,
                                                            s_tail, s_et);

    // hop 0
    score_kernel<<<SCAN_BLOCKS, 256, 0, stream>>>(ent, wrh, wrt, dH, dT);
    hop_kernel<<<NENT / 4, 256, 0, stream>>>(ent, off, cnt, s_tail, s_et, dH, dT,
                                             ent, out, emb_a);
    // hop 1
    score_kernel<<<SCAN_BLOCKS, 256, 0, stream>>>(emb_a, wrh, wrt, dH, dT);
    hop_kernel<<<NENT / 4, 256, 0, stream>>>(emb_a, off, cnt, s_tail, s_et, dH, dT,
                                             out, out, nullptr);
}

// Round 8
// 552.812 us; speedup vs baseline: 1.7303x; 1.1749x over previous
//
#include <hip/hip_runtime.h>
#include <math.h>

#define NENT   100000
#define NREL   50
#define DIM    64
#define NEDGE  1000000
#define RCH    10                             // relations per score-block y-chunk
#define SCAN_BLOCKS ((NENT + 255) / 256)      // 391

// wr[r][d] = sum_k W[d][k] * rel[r][k]  (head half); wrt uses W[64+d][k]
__global__ void wr_kernel(const float* __restrict__ W, const float* __restrict__ rel,
                          float* __restrict__ wrh, float* __restrict__ wrt) {
    int id = blockIdx.x * blockDim.x + threadIdx.x;
    if (id >= NREL * DIM) return;
    int r = id / DIM, d = id % DIM;
    const float* wh = W + (size_t)d * DIM;
    const float* wt = W + (size_t)(DIM + d) * DIM;
    const float* rr = rel + (size_t)r * DIM;
    float ah = 0.f, at = 0.f;
    for (int k = 0; k < DIM; ++k) {
        ah += wh[k] * rr[k];
        at += wt[k] * rr[k];
    }
    wrh[id] = ah;
    wrt[id] = at;
}

// dH[r][e] = dot(emb[e], wrh[r]); dT[r][e] = dot(emb[e], wrt[r])
// grid = (SCAN_BLOCKS, NREL/RCH); transposed layout -> coalesced writes
__global__ __launch_bounds__(256) void score_kernel(
    const float* __restrict__ emb, const float* __restrict__ wrh,
    const float* __restrict__ wrt, float* __restrict__ dH, float* __restrict__ dT) {
    int e = blockIdx.x * 256 + threadIdx.x;
    if (e >= NENT) return;
    float row[DIM];
    const float4* rp = (const float4*)(emb + (size_t)e * DIM);
    #pragma unroll
    for (int q = 0; q < DIM / 4; ++q) {
        float4 v = rp[q];
        row[4 * q] = v.x; row[4 * q + 1] = v.y; row[4 * q + 2] = v.z; row[4 * q + 3] = v.w;
    }
    int r0 = blockIdx.y * RCH;
    for (int rr = 0; rr < RCH; ++rr) {
        int r = r0 + rr;
        const float* wh = wrh + r * DIM;
        const float* wt = wrt + r * DIM;
        float ah = 0.f, at = 0.f;
        #pragma unroll
        for (int k = 0; k < DIM; ++k) {
            ah = fmaf(row[k], wh[k], ah);
            at = fmaf(row[k], wt[k], at);
        }
        dH[(size_t)r * NENT + e] = ah;   // coalesced across lanes
        dT[(size_t)r * NENT + e] = at;
    }
}

// histogram + per-edge rank (removes scatter's atomic)
__global__ void hist_kernel(const int* __restrict__ head, int* __restrict__ cnt,
                            int* __restrict__ rank) {
    int i = blockIdx.x * blockDim.x + threadIdx.x;
    if (i < NEDGE) rank[i] = atomicAdd(&cnt[head[i]], 1);
}

__global__ void scan_block_kernel(const int* __restrict__ cnt, int* __restrict__ off,
                                  int* __restrict__ bsum) {
    __shared__ int s[256];
    int i = blockIdx.x * 256 + threadIdx.x;
    int v = (i < NENT) ? cnt[i] : 0;
    s[threadIdx.x] = v;
    __syncthreads();
    for (int dlt = 1; dlt < 256; dlt <<= 1) {
        int t = (threadIdx.x >= dlt) ? s[threadIdx.x - dlt] : 0;
        __syncthreads();
        s[threadIdx.x] += t;
        __syncthreads();
    }
    if (i < NENT) off[i] = s[threadIdx.x] - v;   // exclusive within block
    if (threadIdx.x == 255) bsum[blockIdx.x] = s[255];
}

// parallel exclusive scan of the 391 block sums (single 512-thread block)
__global__ void scan_bsum_kernel(int* __restrict__ bsum, int nb) {
    __shared__ int s[512];
    int t = threadIdx.x;
    int v = (t < nb) ? bsum[t] : 0;
    s[t] = v;
    __syncthreads();
    for (int d = 1; d < 512; d <<= 1) {
        int x = (t >= d) ? s[t - d] : 0;
        __syncthreads();
        s[t] += x;
        __syncthreads();
    }
    if (t < nb) bsum[t] = s[t] - v;   // exclusive
}

__global__ void add_bsum_kernel(int* __restrict__ off, const int* __restrict__ bsum) {
    int i = blockIdx.x * 256 + threadIdx.x;
    if (i < NENT) off[i] += bsum[blockIdx.x];
}

__global__ void scatter_kernel(const int* __restrict__ head, const int* __restrict__ tail,
                               const int* __restrict__ etype, const int* __restrict__ off,
                               const int* __restrict__ rank, int* __restrict__ s_head,
                               int* __restrict__ s_tail, int* __restrict__ s_et) {
    int i = blockIdx.x * blockDim.x + threadIdx.x;
    if (i >= NEDGE) return;
    int h = head[i];
    int pos = off[h] + rank[i];
    s_head[pos] = h;
    s_tail[pos] = tail[i];
    s_et[pos]   = etype[i];
}

// per-edge post-leaky score, CSR order; full-occupancy gather kernel
__global__ void edge_score_kernel(const int* __restrict__ s_head,
                                  const int* __restrict__ s_tail,
                                  const int* __restrict__ s_et,
                                  const float* __restrict__ dH,
                                  const float* __restrict__ dT,
                                  float* __restrict__ s_sc) {
    int i = blockIdx.x * blockDim.x + threadIdx.x;
    if (i >= NEDGE) return;
    int h = s_head[i], tl = s_tail[i], et = s_et[i];
    float s = dH[(size_t)et * NENT + h] + dT[(size_t)et * NENT + tl];
    s_sc[i] = (s >= 0.f) ? s : 0.2f * s;
}

// One 64-lane wave per head entity. No LDS, no per-edge score math.
__global__ __launch_bounds__(256) void hop_kernel(
    const float* __restrict__ emb, const int* __restrict__ off, const int* __restrict__ cnt,
    const int* __restrict__ s_tail, const float* __restrict__ s_sc,
    const float* __restrict__ res_in, float* __restrict__ res_out,
    float* __restrict__ emb_out) {
    int h    = blockIdx.x * 4 + (threadIdx.x >> 6);
    int lane = threadIdx.x & 63;

    float embH = emb[(size_t)h * DIM + lane];
    int o = off[h], c = cnt[h];

    // phase 1: wave max of scores (lane = edge), coalesced reads
    float mloc = -1e30f;
    for (int j0 = 0; j0 < c; j0 += 64) {
        int j = j0 + lane;
        if (j < c) mloc = fmaxf(mloc, s_sc[o + j]);
    }
    #pragma unroll
    for (int s = 32; s; s >>= 1) mloc = fmaxf(mloc, __shfl_xor(mloc, s, 64));
    float m = mloc;

    // phase 2: denom = sum(w), num[lane] = sum(w * emb[tail][lane]) — 2x unrolled
    float denom = 0.f, num = 0.f;
    int j = 0;
    for (; j + 2 <= c; j += 2) {
        int tl0 = s_tail[o + j];
        int tl1 = s_tail[o + j + 1];
        float e0 = s_sc[o + j];
        float e1 = s_sc[o + j + 1];
        float t0 = emb[(size_t)tl0 * DIM + lane];
        float t1 = emb[(size_t)tl1 * DIM + lane];
        float w0 = __expf(e0 - m);
        float w1 = __expf(e1 - m);
        num = fmaf(w0, t0, num);
        num = fmaf(w1, t1, num);
        denom += w0 + w1;
    }
    if (j < c) {
        int tl = s_tail[o + j];
        float t = emb[(size_t)tl * DIM + lane];
        float w = __expf(s_sc[o + j] - m);
        num = fmaf(w, t, num);
        denom += w;
    }

    float v = embH + ((c > 0) ? (num / denom) : 0.f);

    // L2 normalize across the 64 dims
    float sq = v * v;
    #pragma unroll
    for (int s = 32; s; s >>= 1) sq += __shfl_xor(sq, s, 64);
    float nrm = sqrtf(sq);
    v = v / fmaxf(nrm, 1e-12f);

    if (emb_out) emb_out[(size_t)h * DIM + lane] = v;
    res_out[(size_t)h * DIM + lane] = 0.5f * res_in[(size_t)h * DIM + lane] + v;
}

extern "C" void kernel_launch(void* const* d_in, const int* in_sizes, int n_in,
                              void* d_out, int out_size, void* d_ws, size_t ws_size,
                              hipStream_t stream) {
    const float* ent   = (const float*)d_in[0];
    const float* rel   = (const float*)d_in[1];
    const float* W     = (const float*)d_in[2];
    const int*   head  = (const int*)d_in[3];
    const int*   tail  = (const int*)d_in[4];
    const int*   etype = (const int*)d_in[5];
    float* out = (float*)d_out;

    char* ws = (char*)d_ws;
    size_t pos = 0;
    auto carve = [&](size_t b) -> void* {
        void* p = ws + pos;
        pos += (b + 255) & ~(size_t)255;
        return p;
    };
    float* wrh    = (float*)carve((size_t)NREL * DIM * 4);
    float* wrt    = (float*)carve((size_t)NREL * DIM * 4);
    float* emb_a  = (float*)carve((size_t)NENT * DIM * 4);
    int*   cnt    = (int*)carve((size_t)NENT * 4);
    int*   off    = (int*)carve((size_t)NENT * 4);
    int*   bsum   = (int*)carve((size_t)SCAN_BLOCKS * 4);
    int*   s_head = (int*)carve((size_t)NEDGE * 4);
    int*   s_tail = (int*)carve((size_t)NEDGE * 4);
    int*   s_et   = (int*)carve((size_t)NEDGE * 4);
    int*   rank   = (int*)carve((size_t)NEDGE * 4);
    float* s_sc   = (float*)carve((size_t)NEDGE * 4);
    float* dH     = (float*)carve((size_t)NENT * NREL * 4);
    float* dT     = (float*)carve((size_t)NENT * NREL * 4);

    hipMemsetAsync(cnt, 0, (size_t)NENT * 4, stream);

    wr_kernel<<<(NREL * DIM + 255) / 256, 256, 0, stream>>>(W, rel, wrh, wrt);
    hist_kernel<<<(NEDGE + 255) / 256, 256, 0, stream>>>(head, cnt, rank);
    scan_block_kernel<<<SCAN_BLOCKS, 256, 0, stream>>>(cnt, off, bsum);
    scan_bsum_kernel<<<1, 512, 0, stream>>>(bsum, SCAN_BLOCKS);
    add_bsum_kernel<<<SCAN_BLOCKS, 256, 0, stream>>>(off, bsum);
    scatter_kernel<<<(NEDGE + 255) / 256, 256, 0, stream>>>(head, tail, etype, off, rank,
                                                            s_head, s_tail, s_et);

    dim3 sgrid(SCAN_BLOCKS, NREL / RCH);

    // hop 0
    score_kernel<<<sgrid, 256, 0, stream>>>(ent, wrh, wrt, dH, dT);
    edge_score_kernel<<<(NEDGE + 255) / 256, 256, 0, stream>>>(s_head, s_tail, s_et,
                                                               dH, dT, s_sc);
    hop_kernel<<<NENT / 4, 256, 0, stream>>>(ent, off, cnt, s_tail, s_sc,
                                             ent, out, emb_a);
    // hop 1
    score_kernel<<<sgrid, 256, 0, stream>>>(emb_a, wrh, wrt, dH, dT);
    edge_score_kernel<<<(NEDGE + 255) / 256, 256, 0, stream>>>(s_head, s_tail, s_et,
                                                               dH, dT, s_sc);
    hop_kernel<<<NENT / 4, 256, 0, stream>>>(emb_a, off, cnt, s_tail, s_sc,
                                             out, out, nullptr);
}

// Round 9
// 518.777 us; speedup vs baseline: 1.8438x; 1.0656x over previous
//
#include <hip/hip_runtime.h>
#include <math.h>

#define NENT   100000
#define NREL   50
#define DIM    64
#define NEDGE  1000000
#define RCH    25                             // relations per score-block y-chunk
#define SCAN_BLOCKS ((NENT + 255) / 256)      // 391

// wr[r][d] = sum_k W[d][k] * rel[r][k]  (head half); wrt uses W[64+d][k]
__global__ void wr_kernel(const float* __restrict__ W, const float* __restrict__ rel,
                          float* __restrict__ wrh, float* __restrict__ wrt) {
    int id = blockIdx.x * blockDim.x + threadIdx.x;
    if (id >= NREL * DIM) return;
    int r = id / DIM, d = id % DIM;
    const float* wh = W + (size_t)d * DIM;
    const float* wt = W + (size_t)(DIM + d) * DIM;
    const float* rr = rel + (size_t)r * DIM;
    float ah = 0.f, at = 0.f;
    for (int k = 0; k < DIM; ++k) {
        ah += wh[k] * rr[k];
        at += wt[k] * rr[k];
    }
    wrh[id] = ah;
    wrt[id] = at;
}

// dH[r][e] = dot(emb[e], wrh[r]); dT[r][e] = dot(emb[e], wrt[r])
// grid = (SCAN_BLOCKS, NREL/RCH); 8 independent FMA chains for ILP
__global__ __launch_bounds__(256) void score_kernel(
    const float* __restrict__ emb, const float* __restrict__ wrh,
    const float* __restrict__ wrt, float* __restrict__ dH, float* __restrict__ dT) {
    int e = blockIdx.x * 256 + threadIdx.x;
    if (e >= NENT) return;
    float row[DIM];
    const float4* rp = (const float4*)(emb + (size_t)e * DIM);
    #pragma unroll
    for (int q = 0; q < DIM / 4; ++q) {
        float4 v = rp[q];
        row[4 * q] = v.x; row[4 * q + 1] = v.y; row[4 * q + 2] = v.z; row[4 * q + 3] = v.w;
    }
    int r0 = blockIdx.y * RCH;
    for (int rr = 0; rr < RCH; ++rr) {
        int r = r0 + rr;
        const float* wh = wrh + r * DIM;
        const float* wt = wrt + r * DIM;
        float ah0 = 0.f, ah1 = 0.f, ah2 = 0.f, ah3 = 0.f;
        float at0 = 0.f, at1 = 0.f, at2 = 0.f, at3 = 0.f;
        #pragma unroll
        for (int k = 0; k < 16; ++k) {
            ah0 = fmaf(row[k],      wh[k],      ah0);
            ah1 = fmaf(row[k + 16], wh[k + 16], ah1);
            ah2 = fmaf(row[k + 32], wh[k + 32], ah2);
            ah3 = fmaf(row[k + 48], wh[k + 48], ah3);
            at0 = fmaf(row[k],      wt[k],      at0);
            at1 = fmaf(row[k + 16], wt[k + 16], at1);
            at2 = fmaf(row[k + 32], wt[k + 32], at2);
            at3 = fmaf(row[k + 48], wt[k + 48], at3);
        }
        dH[(size_t)r * NENT + e] = (ah0 + ah1) + (ah2 + ah3);   // coalesced
        dT[(size_t)r * NENT + e] = (at0 + at1) + (at2 + at3);
    }
}

// histogram + per-edge rank (removes scatter's atomic)
__global__ void hist_kernel(const int* __restrict__ head, int* __restrict__ cnt,
                            int* __restrict__ rank) {
    int i = blockIdx.x * blockDim.x + threadIdx.x;
    if (i < NEDGE) rank[i] = atomicAdd(&cnt[head[i]], 1);
}

__global__ void scan_block_kernel(const int* __restrict__ cnt, int* __restrict__ off,
                                  int* __restrict__ bsum) {
    __shared__ int s[256];
    int i = blockIdx.x * 256 + threadIdx.x;
    int v = (i < NENT) ? cnt[i] : 0;
    s[threadIdx.x] = v;
    __syncthreads();
    for (int dlt = 1; dlt < 256; dlt <<= 1) {
        int t = (threadIdx.x >= dlt) ? s[threadIdx.x - dlt] : 0;
        __syncthreads();
        s[threadIdx.x] += t;
        __syncthreads();
    }
    if (i < NENT) off[i] = s[threadIdx.x] - v;   // exclusive within block
    if (threadIdx.x == 255) bsum[blockIdx.x] = s[255];
}

// parallel exclusive scan of the 391 block sums (single 512-thread block)
__global__ void scan_bsum_kernel(int* __restrict__ bsum, int nb) {
    __shared__ int s[512];
    int t = threadIdx.x;
    int v = (t < nb) ? bsum[t] : 0;
    s[t] = v;
    __syncthreads();
    for (int d = 1; d < 512; d <<= 1) {
        int x = (t >= d) ? s[t - d] : 0;
        __syncthreads();
        s[t] += x;
        __syncthreads();
    }
    if (t < nb) bsum[t] = s[t] - v;   // exclusive
}

__global__ void add_bsum_kernel(int* __restrict__ off, const int* __restrict__ bsum) {
    int i = blockIdx.x * 256 + threadIdx.x;
    if (i < NENT) off[i] += bsum[blockIdx.x];
}

// CSR scatter: one 8B write per edge, {tail, etype} packed
__global__ void scatter_kernel(const int* __restrict__ head, const int* __restrict__ tail,
                               const int* __restrict__ etype, const int* __restrict__ off,
                               const int* __restrict__ rank, int2* __restrict__ te) {
    int i = blockIdx.x * blockDim.x + threadIdx.x;
    if (i >= NEDGE) return;
    int pos = off[head[i]] + rank[i];
    te[pos] = make_int2(tail[i], etype[i]);
}

// One 64-lane wave per head entity. Phase 1 (lane=edge) gathers scores and keeps
// them in registers; phase 2 (lane=dim) broadcasts them via shfl (c<=64 fast path).
__global__ __launch_bounds__(256) void hop_kernel(
    const float* __restrict__ emb, const int* __restrict__ off, const int* __restrict__ cnt,
    const int2* __restrict__ te, const float* __restrict__ dH, const float* __restrict__ dT,
    const float* __restrict__ res_in, float* __restrict__ res_out,
    float* __restrict__ emb_out) {
    int h    = blockIdx.x * 4 + (threadIdx.x >> 6);
    int lane = threadIdx.x & 63;

    float embH = emb[(size_t)h * DIM + lane];
    int o = off[h], c = cnt[h];

    // phase 1: per-lane edge scores + wave max
    float sc0 = -1e30f;     // lane's score for edge (o + lane), first round
    float mloc = -1e30f;
    for (int j0 = 0; j0 < c; j0 += 64) {
        int j = j0 + lane;
        float sc = -1e30f;
        if (j < c) {
            int2 p = te[o + j];
            float s = dH[(size_t)p.y * NENT + h] + dT[(size_t)p.y * NENT + p.x];
            sc = (s >= 0.f) ? s : 0.2f * s;
        }
        if (j0 == 0) sc0 = sc;
        mloc = fmaxf(mloc, sc);
    }
    #pragma unroll
    for (int s = 32; s; s >>= 1) mloc = fmaxf(mloc, __shfl_xor(mloc, s, 64));
    float m = mloc;

    // phase 2: denom = sum(w), num[lane] = sum(w * emb[tail][lane])
    float denom = 0.f, num = 0.f;
    if (c <= 64) {
        int j = 0;
        for (; j + 2 <= c; j += 2) {
            int2 p0 = te[o + j];
            int2 p1 = te[o + j + 1];
            float t0 = emb[(size_t)p0.x * DIM + lane];
            float t1 = emb[(size_t)p1.x * DIM + lane];
            float w0 = __expf(__shfl(sc0, j, 64) - m);
            float w1 = __expf(__shfl(sc0, j + 1, 64) - m);
            num = fmaf(w0, t0, num);
            num = fmaf(w1, t1, num);
            denom += w0 + w1;
        }
        if (j < c) {
            int2 p = te[o + j];
            float t = emb[(size_t)p.x * DIM + lane];
            float w = __expf(__shfl(sc0, j, 64) - m);
            num = fmaf(w, t, num);
            denom += w;
        }
    } else {
        // rare fallback: recompute scores per edge (uniform scalar gathers)
        for (int j = 0; j < c; ++j) {
            int2 p = te[o + j];
            float s = dH[(size_t)p.y * NENT + h] + dT[(size_t)p.y * NENT + p.x];
            float e = (s >= 0.f) ? s : 0.2f * s;
            float t = emb[(size_t)p.x * DIM + lane];
            float w = __expf(e - m);
            num = fmaf(w, t, num);
            denom += w;
        }
    }

    float v = embH + ((c > 0) ? (num / denom) : 0.f);

    // L2 normalize across the 64 dims
    float sq = v * v;
    #pragma unroll
    for (int s = 32; s; s >>= 1) sq += __shfl_xor(sq, s, 64);
    float nrm = sqrtf(sq);
    v = v / fmaxf(nrm, 1e-12f);

    if (emb_out) emb_out[(size_t)h * DIM + lane] = v;
    res_out[(size_t)h * DIM + lane] = 0.5f * res_in[(size_t)h * DIM + lane] + v;
}

extern "C" void kernel_launch(void* const* d_in, const int* in_sizes, int n_in,
                              void* d_out, int out_size, void* d_ws, size_t ws_size,
                              hipStream_t stream) {
    const float* ent   = (const float*)d_in[0];
    const float* rel   = (const float*)d_in[1];
    const float* W     = (const float*)d_in[2];
    const int*   head  = (const int*)d_in[3];
    const int*   tail  = (const int*)d_in[4];
    const int*   etype = (const int*)d_in[5];
    float* out = (float*)d_out;

    char* ws = (char*)d_ws;
    size_t pos = 0;
    auto carve = [&](size_t b) -> void* {
        void* p = ws + pos;
        pos += (b + 255) & ~(size_t)255;
        return p;
    };
    float* wrh   = (float*)carve((size_t)NREL * DIM * 4);
    float* wrt   = (float*)carve((size_t)NREL * DIM * 4);
    float* emb_a = (float*)carve((size_t)NENT * DIM * 4);
    int*   cnt   = (int*)carve((size_t)NENT * 4);
    int*   off   = (int*)carve((size_t)NENT * 4);
    int*   bsum  = (int*)carve((size_t)SCAN_BLOCKS * 4);
    int*   rank  = (int*)carve((size_t)NEDGE * 4);
    int2*  te    = (int2*)carve((size_t)NEDGE * 8);
    float* dH    = (float*)carve((size_t)NENT * NREL * 4);
    float* dT    = (float*)carve((size_t)NENT * NREL * 4);

    hipMemsetAsync(cnt, 0, (size_t)NENT * 4, stream);

    wr_kernel<<<(NREL * DIM + 255) / 256, 256, 0, stream>>>(W, rel, wrh, wrt);
    hist_kernel<<<(NEDGE + 255) / 256, 256, 0, stream>>>(head, cnt, rank);
    scan_block_kernel<<<SCAN_BLOCKS, 256, 0, stream>>>(cnt, off, bsum);
    scan_bsum_kernel<<<1, 512, 0, stream>>>(bsum, SCAN_BLOCKS);
    add_bsum_kernel<<<SCAN_BLOCKS, 256, 0, stream>>>(off, bsum);
    scatter_kernel<<<(NEDGE + 255) / 256, 256, 0, stream>>>(head, tail, etype, off, rank, te);

    dim3 sgrid(SCAN_BLOCKS, NREL / RCH);

    // hop 0
    score_kernel<<<sgrid, 256, 0, stream>>>(ent, wrh, wrt, dH, dT);
    hop_kernel<<<NENT / 4, 256, 0, stream>>>(ent, off, cnt, te, dH, dT,
                                             ent, out, emb_a);
    // hop 1
    score_kernel<<<sgrid, 256, 0, stream>>>(emb_a, wrh, wrt, dH, dT);
    hop_kernel<<<NENT / 4, 256, 0, stream>>>(emb_a, off, cnt, te, dH, dT,
                                             out, out, nullptr);
}

// Round 10
// 386.985 us; speedup vs baseline: 2.4718x; 1.3406x over previous
//
#include <hip/hip_runtime.h>
#include <math.h>

#define NENT   100000
#define NREL   50
#define DIM    64
#define NEDGE  1000000
#define RCH    13                             // relations per score-block y-chunk
#define SGY    4                              // grid.y for score (4*13 >= 50)
#define SCAN_BLOCKS ((NENT + 255) / 256)      // 391

// wr[r][d] = sum_k W[d][k] * rel[r][k]  (head half); wrt uses W[64+d][k]
__global__ void wr_kernel(const float* __restrict__ W, const float* __restrict__ rel,
                          float* __restrict__ wrh, float* __restrict__ wrt) {
    int id = blockIdx.x * blockDim.x + threadIdx.x;
    if (id >= NREL * DIM) return;
    int r = id / DIM, d = id % DIM;
    const float* wh = W + (size_t)d * DIM;
    const float* wt = W + (size_t)(DIM + d) * DIM;
    const float* rr = rel + (size_t)r * DIM;
    float ah = 0.f, at = 0.f;
    for (int k = 0; k < DIM; ++k) {
        ah += wh[k] * rr[k];
        at += wt[k] * rr[k];
    }
    wrh[id] = ah;
    wrt[id] = at;
}

// dH[r][e] = dot(emb[e], wrh[r]); dT[r][e] = dot(emb[e], wrt[r])
// float4 weight loads: 32 vmem per relation instead of 128 scalars
__global__ __launch_bounds__(256) void score_kernel(
    const float* __restrict__ emb, const float* __restrict__ wrh,
    const float* __restrict__ wrt, float* __restrict__ dH, float* __restrict__ dT) {
    int e = blockIdx.x * 256 + threadIdx.x;
    if (e >= NENT) return;
    float4 row4[16];
    const float4* rp = (const float4*)(emb + (size_t)e * DIM);
    #pragma unroll
    for (int qq = 0; qq < 16; ++qq) row4[qq] = rp[qq];
    int r0 = blockIdx.y * RCH;
    for (int rr = 0; rr < RCH; ++rr) {
        int r = r0 + rr;
        if (r >= NREL) break;
        const float4* wh4 = (const float4*)(wrh + (size_t)r * DIM);
        const float4* wt4 = (const float4*)(wrt + (size_t)r * DIM);
        float4 ah = make_float4(0.f, 0.f, 0.f, 0.f);
        float4 at = make_float4(0.f, 0.f, 0.f, 0.f);
        #pragma unroll
        for (int qq = 0; qq < 16; ++qq) {
            float4 w = wh4[qq];
            float4 x = wt4[qq];
            float4 rv = row4[qq];
            ah.x = fmaf(rv.x, w.x, ah.x);
            ah.y = fmaf(rv.y, w.y, ah.y);
            ah.z = fmaf(rv.z, w.z, ah.z);
            ah.w = fmaf(rv.w, w.w, ah.w);
            at.x = fmaf(rv.x, x.x, at.x);
            at.y = fmaf(rv.y, x.y, at.y);
            at.z = fmaf(rv.z, x.z, at.z);
            at.w = fmaf(rv.w, x.w, at.w);
        }
        dH[(size_t)r * NENT + e] = (ah.x + ah.y) + (ah.z + ah.w);   // coalesced
        dT[(size_t)r * NENT + e] = (at.x + at.y) + (at.z + at.w);
    }
}

// histogram + per-edge rank (removes scatter's atomic)
__global__ void hist_kernel(const int* __restrict__ head, int* __restrict__ cnt,
                            int* __restrict__ rank) {
    int i = blockIdx.x * blockDim.x + threadIdx.x;
    if (i < NEDGE) rank[i] = atomicAdd(&cnt[head[i]], 1);
}

__global__ void scan_block_kernel(const int* __restrict__ cnt, int* __restrict__ off,
                                  int* __restrict__ bsum) {
    __shared__ int s[256];
    int i = blockIdx.x * 256 + threadIdx.x;
    int v = (i < NENT) ? cnt[i] : 0;
    s[threadIdx.x] = v;
    __syncthreads();
    for (int dlt = 1; dlt < 256; dlt <<= 1) {
        int t = (threadIdx.x >= dlt) ? s[threadIdx.x - dlt] : 0;
        __syncthreads();
        s[threadIdx.x] += t;
        __syncthreads();
    }
    if (i < NENT) off[i] = s[threadIdx.x] - v;   // exclusive within block
    if (threadIdx.x == 255) bsum[blockIdx.x] = s[255];
}

// parallel exclusive scan of the 391 block sums (single 512-thread block)
__global__ void scan_bsum_kernel(int* __restrict__ bsum, int nb) {
    __shared__ int s[512];
    int t = threadIdx.x;
    int v = (t < nb) ? bsum[t] : 0;
    s[t] = v;
    __syncthreads();
    for (int d = 1; d < 512; d <<= 1) {
        int x = (t >= d) ? s[t - d] : 0;
        __syncthreads();
        s[t] += x;
        __syncthreads();
    }
    if (t < nb) bsum[t] = s[t] - v;   // exclusive
}

__global__ void add_bsum_kernel(int* __restrict__ off, const int* __restrict__ bsum) {
    int i = blockIdx.x * 256 + threadIdx.x;
    if (i < NENT) off[i] += bsum[blockIdx.x];
}

// CSR scatter: one 8B write per edge, {tail, etype} packed
__global__ void scatter_kernel(const int* __restrict__ head, const int* __restrict__ tail,
                               const int* __restrict__ etype, const int* __restrict__ off,
                               const int* __restrict__ rank, int2* __restrict__ te) {
    int i = blockIdx.x * blockDim.x + threadIdx.x;
    if (i >= NEDGE) return;
    int pos = off[head[i]] + rank[i];
    te[pos] = make_int2(tail[i], etype[i]);
}

// One 64-lane wave per head entity.
// Phase 1 (lane=edge): gather scores, keep first 64 in regs, wave max.
// Phase 2: 4 edges in flight, 16 lanes each (lane = 16*q + d); float4 row loads.
__global__ __launch_bounds__(256) void hop_kernel(
    const float* __restrict__ emb, const int* __restrict__ off, const int* __restrict__ cnt,
    const int2* __restrict__ te, const float* __restrict__ dH, const float* __restrict__ dT,
    const float* __restrict__ res_in, float* __restrict__ res_out,
    float* __restrict__ emb_out) {
    int h    = blockIdx.x * 4 + (threadIdx.x >> 6);
    int lane = threadIdx.x & 63;
    int q    = lane >> 4;      // edge slot 0..3
    int d    = lane & 15;      // dim-quad 0..15

    int o = off[h], c = cnt[h];

    // phase 1: per-lane edge scores + wave max (lane = edge)
    float sc0 = -1e30f;
    int   tl0 = 0;
    float mloc = -1e30f;
    for (int j0 = 0; j0 < c; j0 += 64) {
        int j = j0 + lane;
        float sc = -1e30f;
        int tl = 0;
        if (j < c) {
            int2 p = te[o + j];
            tl = p.x;
            float s = dH[(size_t)p.y * NENT + h] + dT[(size_t)p.y * NENT + p.x];
            sc = (s >= 0.f) ? s : 0.2f * s;
        }
        if (j0 == 0) { sc0 = sc; tl0 = tl; }
        mloc = fmaxf(mloc, sc);
    }
    #pragma unroll
    for (int s = 32; s; s >>= 1) mloc = fmaxf(mloc, __shfl_xor(mloc, s, 64));
    float m = mloc;

    // phase 2: acc[d*4..d*4+3] = sum(w * emb[tail][.]) over edges j==q (mod 4)
    float4 acc = make_float4(0.f, 0.f, 0.f, 0.f);
    float denom = 0.f;
    int c64 = (c < 64) ? c : 64;
    for (int j = 0; j < c64; j += 4) {
        int  jq    = j + q;
        bool valid = jq < c64;
        int  idx   = valid ? jq : 0;
        int   tl = __shfl(tl0, idx, 64);
        float sc = __shfl(sc0, idx, 64);
        float w  = valid ? __expf(sc - m) : 0.f;
        if (valid) {
            float4 t = *(const float4*)(emb + (size_t)tl * DIM + d * 4);
            acc.x = fmaf(w, t.x, acc.x);
            acc.y = fmaf(w, t.y, acc.y);
            acc.z = fmaf(w, t.z, acc.z);
            acc.w = fmaf(w, t.w, acc.w);
        }
        denom += w;
    }
    // reduce the 4 q-groups (lane bits 4,5)
    #pragma unroll
    for (int s = 16; s <= 32; s <<= 1) {
        acc.x += __shfl_xor(acc.x, s, 64);
        acc.y += __shfl_xor(acc.y, s, 64);
        acc.z += __shfl_xor(acc.z, s, 64);
        acc.w += __shfl_xor(acc.w, s, 64);
        denom += __shfl_xor(denom, s, 64);
    }
    // rare overflow path (c > 64): uniform per-edge accumulation, identical across lanes/groups
    if (c > 64) {
        for (int j = 64; j < c; ++j) {
            int2 p = te[o + j];
            float s = dH[(size_t)p.y * NENT + h] + dT[(size_t)p.y * NENT + p.x];
            float e = (s >= 0.f) ? s : 0.2f * s;
            float w = __expf(e - m);
            float4 t = *(const float4*)(emb + (size_t)p.x * DIM + d * 4);
            acc.x = fmaf(w, t.x, acc.x);
            acc.y = fmaf(w, t.y, acc.y);
            acc.z = fmaf(w, t.z, acc.z);
            acc.w = fmaf(w, t.w, acc.w);
            denom += w;
        }
    }

    float4 embH4 = *(const float4*)(emb + (size_t)h * DIM + d * 4);
    float inv = (c > 0) ? (1.f / denom) : 0.f;
    float4 v4;
    v4.x = embH4.x + acc.x * inv;
    v4.y = embH4.y + acc.y * inv;
    v4.z = embH4.z + acc.z * inv;
    v4.w = embH4.w + acc.w * inv;

    // L2 norm over 64 dims: reduce over d (lane bits 0..3)
    float sq = v4.x * v4.x + v4.y * v4.y + v4.z * v4.z + v4.w * v4.w;
    #pragma unroll
    for (int s = 1; s <= 8; s <<= 1) sq += __shfl_xor(sq, s, 64);
    float innrm = 1.f / fmaxf(sqrtf(sq), 1e-12f);
    v4.x *= innrm; v4.y *= innrm; v4.z *= innrm; v4.w *= innrm;

    if (q == 0) {   // 16 lanes write the 64-dim row as float4
        size_t base = (size_t)h * DIM + d * 4;
        if (emb_out) *(float4*)(emb_out + base) = v4;
        float4 r4 = *(const float4*)(res_in + base);
        float4 o4;
        o4.x = 0.5f * r4.x + v4.x;
        o4.y = 0.5f * r4.y + v4.y;
        o4.z = 0.5f * r4.z + v4.z;
        o4.w = 0.5f * r4.w + v4.w;
        *(float4*)(res_out + base) = o4;
    }
}

extern "C" void kernel_launch(void* const* d_in, const int* in_sizes, int n_in,
                              void* d_out, int out_size, void* d_ws, size_t ws_size,
                              hipStream_t stream) {
    const float* ent   = (const float*)d_in[0];
    const float* rel   = (const float*)d_in[1];
    const float* W     = (const float*)d_in[2];
    const int*   head  = (const int*)d_in[3];
    const int*   tail  = (const int*)d_in[4];
    const int*   etype = (const int*)d_in[5];
    float* out = (float*)d_out;

    char* ws = (char*)d_ws;
    size_t pos = 0;
    auto carve = [&](size_t b) -> void* {
        void* p = ws + pos;
        pos += (b + 255) & ~(size_t)255;
        return p;
    };
    float* wrh   = (float*)carve((size_t)NREL * DIM * 4);
    float* wrt   = (float*)carve((size_t)NREL * DIM * 4);
    float* emb_a = (float*)carve((size_t)NENT * DIM * 4);
    int*   cnt   = (int*)carve((size_t)NENT * 4);
    int*   off   = (int*)carve((size_t)NENT * 4);
    int*   bsum  = (int*)carve((size_t)SCAN_BLOCKS * 4);
    int*   rank  = (int*)carve((size_t)NEDGE * 4);
    int2*  te    = (int2*)carve((size_t)NEDGE * 8);
    float* dH    = (float*)carve((size_t)NENT * NREL * 4);
    float* dT    = (float*)carve((size_t)NENT * NREL * 4);

    hipMemsetAsync(cnt, 0, (size_t)NENT * 4, stream);

    wr_kernel<<<(NREL * DIM + 255) / 256, 256, 0, stream>>>(W, rel, wrh, wrt);
    hist_kernel<<<(NEDGE + 255) / 256, 256, 0, stream>>>(head, cnt, rank);
    scan_block_kernel<<<SCAN_BLOCKS, 256, 0, stream>>>(cnt, off, bsum);
    scan_bsum_kernel<<<1, 512, 0, stream>>>(bsum, SCAN_BLOCKS);
    add_bsum_kernel<<<SCAN_BLOCKS, 256, 0, stream>>>(off, bsum);
    scatter_kernel<<<(NEDGE + 255) / 256, 256, 0, stream>>>(head, tail, etype, off, rank, te);

    dim3 sgrid(SCAN_BLOCKS, SGY);

    // hop 0
    score_kernel<<<sgrid, 256, 0, stream>>>(ent, wrh, wrt, dH, dT);
    hop_kernel<<<NENT / 4, 256, 0, stream>>>(ent, off, cnt, te, dH, dT,
                                             ent, out, emb_a);
    // hop 1
    score_kernel<<<sgrid, 256, 0, stream>>>(emb_a, wrh, wrt, dH, dT);
    hop_kernel<<<NENT / 4, 256, 0, stream>>>(emb_a, off, cnt, te, dH, dT,
                                             out, out, nullptr);
}